// Round 2
// baseline (191.626 us; speedup 1.0000x reference)
//
#include <hip/hip_runtime.h>
#include <cstdint>
#include <cstring>

#define B_ 32
#define N_ 128
#define F_ 128
#define SPLIT_ 4

typedef __attribute__((ext_vector_type(8))) __bf16 bf16x8;
typedef __attribute__((ext_vector_type(4))) float f32x4;

__device__ inline uint16_t f2bf_bits(float f) {
  __bf16 h = (__bf16)f;
  uint16_t u;
  __builtin_memcpy(&u, &h, 2);
  return u;
}

// ---------------- Kernel A: e_v = v_in @ W_ev + b_ev  -> ws ----------------
__global__ __launch_bounds__(128) void ev_kernel(const float* __restrict__ v_in,
                                                 const float* __restrict__ W_ev,
                                                 const float* __restrict__ b_ev,
                                                 float* __restrict__ e_v) {
  __shared__ float vr[8][F_];
  const int R0 = blockIdx.x * 8;
  const int tid = threadIdx.x;  // output feature g
#pragma unroll
  for (int i = 0; i < 8; ++i) vr[i][tid] = v_in[(size_t)(R0 + i) * F_ + tid];
  __syncthreads();
  float acc[8];
  const float bb = b_ev[tid];
#pragma unroll
  for (int i = 0; i < 8; ++i) acc[i] = bb;
  for (int f = 0; f < F_; ++f) {
    const float wv = W_ev[f * F_ + tid];
#pragma unroll
    for (int i = 0; i < 8; ++i) acc[i] += vr[i][f] * wv;
  }
#pragma unroll
  for (int i = 0; i < 8; ++i) e_v[(size_t)(R0 + i) * F_ + tid] = acc[i];
}

// ------- Kernel P: pack W_e (fp32 [128][128]) into bf16 MFMA fragments ------
// Tile t = kt*8+gt. Lane l holds 8 bf16: W_e[kt*32 + 8*(l>>4) + e][gt*16 + (l&15)].
// (Same fragment serves as the A-operand of the swapped GEMM Wt @ e_t.)
__global__ void pack_kernel(const float* __restrict__ W_e, uint32_t* __restrict__ wp) {
  const int idx = blockIdx.x * 256 + threadIdx.x;  // 0..2047
  const int t = idx >> 6, l = idx & 63;
  const int kt = t >> 3, gt = t & 7;
  const int kbase = kt * 32 + ((l >> 4) << 3);
  const int g = gt * 16 + (l & 15);
#pragma unroll
  for (int p = 0; p < 4; ++p) {
    const uint32_t lo = f2bf_bits(W_e[(kbase + 2 * p) * F_ + g]);
    const uint32_t hi = f2bf_bits(W_e[(kbase + 2 * p + 1) * F_ + g]);
    wp[idx * 4 + p] = lo | (hi << 16);
  }
}

// ---------------- Kernel M: fused edge GEMM + epilogue ----------------------
// grid = 32(b) * 8(n-tile) * 4(m-split), 256 threads = 4 waves.
// Swapped MFMA: D = W^T(16g x 32k) * e^T(32k x 16n) -> lane holds
// n = n0 + (l&15), g = gt*16 + (l>>4)*4 + q  => f32x4 stores along g.
__global__ __launch_bounds__(256, 4) void main_kernel(
    const float* __restrict__ e_in, const float* __restrict__ e_v,
    const float* __restrict__ b_e, const bf16x8* __restrict__ wp,
    float* __restrict__ e_out, float* __restrict__ pve_part) {
  __shared__ bf16x8 wfrag[2048];   // 32 KB packed W_e
  __shared__ float comb[16][132];  // evn rows (padded), reused for pve reduce

  const int tid = threadIdx.x;
  const int w = tid >> 6, l = tid & 63;
  const int bid = blockIdx.x;
  const int s = bid & 3;
  const int nt = (bid >> 2) & 7;
  const int b = bid >> 5;
  const int n0 = nt * 16;
  const int lr = (l >> 4) << 2;  // g sub-base within g-tile
  const int lc = l & 15;         // n within n-tile

  for (int i = tid; i < 2048; i += 256) wfrag[i] = wp[i];

  // evn[r][g] = e_v[b][n0+r][g] + b_e[g]  (read back per chunk, padded rows)
  for (int i = tid; i < 2048; i += 256) {
    const int r = i >> 7, g = i & 127;
    comb[r][g] = e_v[((size_t)(b * N_ + n0) + r) * F_ + g] + b_e[g];
  }

  f32x4 pve[8];
#pragma unroll
  for (int gt = 0; gt < 8; ++gt) {
    pve[gt][0] = 0.f; pve[gt][1] = 0.f; pve[gt][2] = 0.f; pve[gt][3] = 0.f;
  }

  __syncthreads();

  const float* einb = e_in + (size_t)b * N_ * N_ * F_;
  float* eoutb = e_out + (size_t)b * N_ * N_ * F_;
  const float* evmb = e_v + (size_t)b * N_ * F_;

  for (int it = 0; it < 8; ++it) {
    const int m = s * 32 + it * 4 + w;
    const float* rowp = einb + ((size_t)m * N_ + n0 + lc) * F_ + ((l >> 4) << 3);
    f32x4 fa0[4], fa1[4];
#pragma unroll
    for (int kt = 0; kt < 4; ++kt) {
      fa0[kt] = *reinterpret_cast<const f32x4*>(rowp + kt * 32);
      fa1[kt] = *reinterpret_cast<const f32x4*>(rowp + kt * 32 + 4);
    }
    bf16x8 a[4];
#pragma unroll
    for (int kt = 0; kt < 4; ++kt) {
#pragma unroll
      for (int e = 0; e < 4; ++e) {
        a[kt][e] = (__bf16)fa0[kt][e];
        a[kt][e + 4] = (__bf16)fa1[kt][e];
      }
    }

    f32x4 acc[8];
#pragma unroll
    for (int gt = 0; gt < 8; ++gt) {
      acc[gt][0] = 0.f; acc[gt][1] = 0.f; acc[gt][2] = 0.f; acc[gt][3] = 0.f;
    }
#pragma unroll
    for (int kt = 0; kt < 4; ++kt)
#pragma unroll
      for (int gt = 0; gt < 8; ++gt)
        acc[gt] = __builtin_amdgcn_mfma_f32_16x16x32_bf16(
            wfrag[(kt * 8 + gt) * 64 + l], a[kt], acc[gt], 0, 0, 0);

    const float* evmr = evmb + (size_t)m * F_;
    float* outp = eoutb + ((size_t)m * N_ + n0 + lc) * F_;
#pragma unroll
    for (int gt = 0; gt < 8; ++gt) {
      const f32x4 evm = *reinterpret_cast<const f32x4*>(evmr + gt * 16 + lr);
      const f32x4 evn = *reinterpret_cast<const f32x4*>(&comb[lc][gt * 16 + lr]);
      f32x4 v = acc[gt] + evn + evm;
#pragma unroll
      for (int q = 0; q < 4; ++q) v[q] = fmaxf(v[q], 0.f);
      pve[gt] += v;
      *reinterpret_cast<f32x4*>(outp + gt * 16 + lr) = v;
    }
  }

  // cross-wave reduce pve into comb (reuse), then dump partial to ws
  __syncthreads();
  for (int t = 0; t < 4; ++t) {
    if (w == t) {
#pragma unroll
      for (int gt = 0; gt < 8; ++gt) {
        f32x4* cp = reinterpret_cast<f32x4*>(&comb[lc][gt * 16 + lr]);
        if (t == 0) *cp = pve[gt];
        else *cp += pve[gt];
      }
    }
    __syncthreads();
  }

  float* pp = pve_part + (((size_t)s * B_ + b) * N_ + n0) * F_;
  for (int i = tid; i < 512; i += 256) {
    const int r = i >> 5, c = (i & 31) << 2;
    reinterpret_cast<f32x4*>(pp)[i] = *reinterpret_cast<f32x4*>(&comb[r][c]);
  }
}

// ---------------- Kernel V: v_out = relu([sum(pve), v_in] @ W_v + b_v) ------
__global__ __launch_bounds__(128) void v_kernel(
    const float* __restrict__ v_in, const float* __restrict__ pve_part,
    const float* __restrict__ W_v, const float* __restrict__ b_v,
    float* __restrict__ v_out) {
  __shared__ float rows[8][256];
  const int R0 = blockIdx.x * 8;
  const int tid = threadIdx.x;
#pragma unroll
  for (int i = 0; i < 8; ++i) {
    const size_t r = R0 + i;
    float acc = 0.f;
#pragma unroll
    for (int s = 0; s < SPLIT_; ++s)
      acc += pve_part[((size_t)s * B_ * N_ + r) * F_ + tid];
    rows[i][tid] = acc;
    rows[i][128 + tid] = v_in[r * F_ + tid];
  }
  __syncthreads();
  float acc[8];
  const float bb = b_v[tid];
#pragma unroll
  for (int i = 0; i < 8; ++i) acc[i] = bb;
  for (int f = 0; f < 256; ++f) {
    const float wv = W_v[f * F_ + tid];
#pragma unroll
    for (int i = 0; i < 8; ++i) acc[i] += rows[i][f] * wv;
  }
#pragma unroll
  for (int i = 0; i < 8; ++i)
    v_out[(size_t)(R0 + i) * F_ + tid] = fmaxf(acc[i], 0.f);
}

extern "C" void kernel_launch(void* const* d_in, const int* in_sizes, int n_in,
                              void* d_out, int out_size, void* d_ws, size_t ws_size,
                              hipStream_t stream) {
  const float* v_in = (const float*)d_in[0];
  const float* e_in = (const float*)d_in[1];
  const float* W_ev = (const float*)d_in[2];
  const float* b_ev = (const float*)d_in[3];
  const float* W_e  = (const float*)d_in[4];
  const float* b_e  = (const float*)d_in[5];
  const float* W_v  = (const float*)d_in[6];
  const float* b_v  = (const float*)d_in[7];

  float* out = (float*)d_out;
  float* v_out = out;                         // [32,128,128]
  float* e_out = out + (size_t)B_ * N_ * F_;  // [32,128,128,128]

  char* ws = (char*)d_ws;
  float* e_v = (float*)ws;                                   // 2 MB
  uint32_t* wpack = (uint32_t*)(ws + (size_t)2097152);       // 32 KB
  float* pve_part = (float*)(ws + (size_t)2097152 + 65536);  // 8 MB

  ev_kernel<<<(B_ * N_) / 8, 128, 0, stream>>>(v_in, W_ev, b_ev, e_v);
  pack_kernel<<<8, 256, 0, stream>>>(W_e, wpack);
  main_kernel<<<B_ * 8 * SPLIT_, 256, 0, stream>>>(e_in, e_v, b_e,
                                                   (const bf16x8*)wpack,
                                                   e_out, pve_part);
  v_kernel<<<(B_ * N_) / 8, 128, 0, stream>>>(v_in, pve_part, W_v, b_v, v_out);
}

// Round 3
// 157.868 us; speedup vs baseline: 1.2138x; 1.2138x over previous
//
#include <hip/hip_runtime.h>
#include <cstdint>
#include <cstring>

#define B_ 32
#define N_ 128
#define F_ 128
#define SPLIT_ 4

typedef __attribute__((ext_vector_type(8))) __bf16 bf16x8;
typedef __attribute__((ext_vector_type(4))) float f32x4;

__device__ inline uint16_t f2bf_bits(float f) {
  __bf16 h = (__bf16)f;
  uint16_t u;
  __builtin_memcpy(&u, &h, 2);
  return u;
}

// async global->LDS, 16B per lane; dst is wave-uniform base (HW adds lane*16)
__device__ inline void gld16(const float* src, float* dst) {
  __builtin_amdgcn_global_load_lds(
      (const __attribute__((address_space(1))) unsigned int*)src,
      (__attribute__((address_space(3))) unsigned int*)dst, 16, 0, 0);
}

// ---------------- Kernel A: e_v = v_in @ W_ev + b_ev  -> ws ----------------
__global__ __launch_bounds__(128) void ev_kernel(const float* __restrict__ v_in,
                                                 const float* __restrict__ W_ev,
                                                 const float* __restrict__ b_ev,
                                                 float* __restrict__ e_v) {
  __shared__ float vr[8][F_];
  const int R0 = blockIdx.x * 8;
  const int tid = threadIdx.x;  // output feature g
#pragma unroll
  for (int i = 0; i < 8; ++i) vr[i][tid] = v_in[(size_t)(R0 + i) * F_ + tid];
  __syncthreads();
  float acc[8];
  const float bb = b_ev[tid];
#pragma unroll
  for (int i = 0; i < 8; ++i) acc[i] = bb;
  for (int f = 0; f < F_; ++f) {
    const float wv = W_ev[f * F_ + tid];
#pragma unroll
    for (int i = 0; i < 8; ++i) acc[i] += vr[i][f] * wv;
  }
#pragma unroll
  for (int i = 0; i < 8; ++i) e_v[(size_t)(R0 + i) * F_ + tid] = acc[i];
}

// ------- Kernel P: pack W_e (fp32 [128][128]) into bf16 MFMA fragments ------
// Tile t = kt*8+gt. Lane l holds 8 bf16: W_e[kt*32 + 8*(l>>4) + e][gt*16 + (l&15)].
__global__ void pack_kernel(const float* __restrict__ W_e, uint32_t* __restrict__ wp) {
  const int idx = blockIdx.x * 256 + threadIdx.x;  // 0..2047
  const int t = idx >> 6, l = idx & 63;
  const int kt = t >> 3, gt = t & 7;
  const int kbase = kt * 32 + ((l >> 4) << 3);
  const int g = gt * 16 + (l & 15);
#pragma unroll
  for (int p = 0; p < 4; ++p) {
    const uint32_t lo = f2bf_bits(W_e[(kbase + 2 * p) * F_ + g]);
    const uint32_t hi = f2bf_bits(W_e[(kbase + 2 * p + 1) * F_ + g]);
    wp[idx * 4 + p] = lo | (hi << 16);
  }
}

// ---------------- Kernel M: fused edge GEMM + epilogue ----------------------
// grid = 32(b) * 8(n-tile) * 4(m-split), 512 threads = 8 waves.
// Per iteration: 2 m rows staged fp32 into LDS (global_load_lds, src-swizzled),
// wave w computes m-parity (w&1), g-quarter (w>>1).  2-phase double buffer.
__global__ __launch_bounds__(512, 4) void main_kernel(
    const float* __restrict__ e_in, const float* __restrict__ e_v,
    const float* __restrict__ b_e, const bf16x8* __restrict__ wp,
    float* __restrict__ e_out, float* __restrict__ pve_part) {
  __shared__ __align__(16) float buf[2 * 2 * 2048];  // 32 KB [dbuf][m][16x128 swz]

  const int tid = threadIdx.x;
  const int w = tid >> 6, l = tid & 63;
  const int bid = blockIdx.x;
  const int s = bid & 3, nt = (bid >> 2) & 7, b = bid >> 5;
  const int n0 = nt * 16;
  const int lr = (l >> 4) << 2;  // g sub-base
  const int lc = l & 15;         // n within n-tile
  const int ml = w & 1;          // compute: m parity
  const int gq = w >> 1;         // compute: g quarter (2 g-tiles)
  const int m0base = s * 32;

  // loop-invariant W fragments in registers (8 x 16B, coalesced loads)
  bf16x8 wreg[4][2];
#pragma unroll
  for (int kt = 0; kt < 4; ++kt)
#pragma unroll
    for (int j = 0; j < 2; ++j)
      wreg[kt][j] = wp[(kt * 8 + gq * 2 + j) * 64 + l];

  // loop-invariant row epilogue term: e_v[b][n0+lc][g] + b_e[g]
  f32x4 evn[2];
#pragma unroll
  for (int j = 0; j < 2; ++j) {
    const int g0 = (gq * 2 + j) * 16 + lr;
    evn[j] = *reinterpret_cast<const f32x4*>(&e_v[(size_t)(b * N_ + n0 + lc) * F_ + g0]) +
             *reinterpret_cast<const f32x4*>(&b_e[g0]);
  }

  f32x4 pve[2];
#pragma unroll
  for (int j = 0; j < 2; ++j) { pve[j][0] = 0.f; pve[j][1] = 0.f; pve[j][2] = 0.f; pve[j][3] = 0.f; }

  // staging lane constants
  const int sw = w >> 2;    // staging m_local (waves 0-3 -> m0, 4-7 -> m1)
  const int ci = l & 31;    // 16B chunk within row
  const int rpar = l >> 5;  // row parity within 1KB chunk
  const float* einb = e_in + (size_t)b * N_ * N_ * F_;

#define STAGE(pp, it2)                                                        \
  {                                                                           \
    const int m_ = m0base + (it2) * 2 + sw;                                   \
    const float* mb_ = einb + ((size_t)m_ * N_ + n0) * F_;                    \
    _Pragma("unroll") for (int j_ = 0; j_ < 2; ++j_) {                        \
      const int cc_ = ((w << 1) | j_) & 7;                                    \
      const int r_ = (cc_ << 1) | rpar;                                       \
      const int sc_ = ci ^ (r_ & 7);                                          \
      gld16(mb_ + r_ * F_ + sc_ * 4, &buf[(pp) * 4096 + sw * 2048 + (cc_ << 8)]); \
    }                                                                         \
  }

  STAGE(0, 0);

  const int swz = lc & 7;
  for (int it = 0; it < 16; ++it) {
    const int p = it & 1;
    __syncthreads();               // buf[p] ready; prior readers done
    if (it < 15) STAGE(p ^ 1, it + 1);  // async prefetch under compute

    const int fbase = p * 4096 + ml * 2048 + lc * 128;
    f32x4 acc[2];
#pragma unroll
    for (int j = 0; j < 2; ++j) { acc[j][0] = 0.f; acc[j][1] = 0.f; acc[j][2] = 0.f; acc[j][3] = 0.f; }

#pragma unroll
    for (int kt = 0; kt < 4; ++kt) {
      const int cA = kt * 8 + ((l >> 4) << 1);
      const f32x4 f0 = *reinterpret_cast<const f32x4*>(&buf[fbase + ((cA ^ swz) << 2)]);
      const f32x4 f1 = *reinterpret_cast<const f32x4*>(&buf[fbase + (((cA + 1) ^ swz) << 2)]);
      bf16x8 a;
#pragma unroll
      for (int e = 0; e < 4; ++e) {
        a[e] = (__bf16)f0[e];
        a[e + 4] = (__bf16)f1[e];
      }
      acc[0] = __builtin_amdgcn_mfma_f32_16x16x32_bf16(wreg[kt][0], a, acc[0], 0, 0, 0);
      acc[1] = __builtin_amdgcn_mfma_f32_16x16x32_bf16(wreg[kt][1], a, acc[1], 0, 0, 0);
    }

    const int m = m0base + it * 2 + ml;
    const float* evm = &e_v[((size_t)b * N_ + m) * F_];
    float* op = e_out + (((size_t)(b * N_) + m) * N_ + n0 + lc) * F_;
#pragma unroll
    for (int j = 0; j < 2; ++j) {
      const int g0 = (gq * 2 + j) * 16 + lr;
      f32x4 v = acc[j] + evn[j] + *reinterpret_cast<const f32x4*>(&evm[g0]);
#pragma unroll
      for (int q = 0; q < 4; ++q) v[q] = fmaxf(v[q], 0.f);
      pve[j] += v;
      *reinterpret_cast<f32x4*>(&op[g0]) = v;
    }
  }

  // pve reduce: even-parity waves write, odd-parity waves add + store partial
  __syncthreads();
  const int sbase = gq * 512 + lc * 32;
  if (ml == 0) {
#pragma unroll
    for (int j = 0; j < 2; ++j)
      *reinterpret_cast<f32x4*>(&buf[sbase + j * 16 + lr]) = pve[j];
  }
  __syncthreads();
  if (ml == 1) {
    float* pp = pve_part + (((size_t)s * B_ + b) * N_ + n0 + lc) * F_;
#pragma unroll
    for (int j = 0; j < 2; ++j) {
      const f32x4 sum = pve[j] + *reinterpret_cast<const f32x4*>(&buf[sbase + j * 16 + lr]);
      *reinterpret_cast<f32x4*>(&pp[(gq * 2 + j) * 16 + lr]) = sum;
    }
  }
#undef STAGE
}

// ---------------- Kernel V: v_out = relu([sum(pve), v_in] @ W_v + b_v) ------
__global__ __launch_bounds__(128) void v_kernel(
    const float* __restrict__ v_in, const float* __restrict__ pve_part,
    const float* __restrict__ W_v, const float* __restrict__ b_v,
    float* __restrict__ v_out) {
  __shared__ float rows[8][256];
  const int R0 = blockIdx.x * 8;
  const int tid = threadIdx.x;
#pragma unroll
  for (int i = 0; i < 8; ++i) {
    const size_t r = R0 + i;
    float acc = 0.f;
#pragma unroll
    for (int s = 0; s < SPLIT_; ++s)
      acc += pve_part[((size_t)s * B_ * N_ + r) * F_ + tid];
    rows[i][tid] = acc;
    rows[i][128 + tid] = v_in[r * F_ + tid];
  }
  __syncthreads();
  float acc[8];
  const float bb = b_v[tid];
#pragma unroll
  for (int i = 0; i < 8; ++i) acc[i] = bb;
  for (int f = 0; f < 256; ++f) {
    const float wv = W_v[f * F_ + tid];
#pragma unroll
    for (int i = 0; i < 8; ++i) acc[i] += rows[i][f] * wv;
  }
#pragma unroll
  for (int i = 0; i < 8; ++i)
    v_out[(size_t)(R0 + i) * F_ + tid] = fmaxf(acc[i], 0.f);
}

extern "C" void kernel_launch(void* const* d_in, const int* in_sizes, int n_in,
                              void* d_out, int out_size, void* d_ws, size_t ws_size,
                              hipStream_t stream) {
  const float* v_in = (const float*)d_in[0];
  const float* e_in = (const float*)d_in[1];
  const float* W_ev = (const float*)d_in[2];
  const float* b_ev = (const float*)d_in[3];
  const float* W_e  = (const float*)d_in[4];
  const float* b_e  = (const float*)d_in[5];
  const float* W_v  = (const float*)d_in[6];
  const float* b_v  = (const float*)d_in[7];

  float* out = (float*)d_out;
  float* v_out = out;                         // [32,128,128]
  float* e_out = out + (size_t)B_ * N_ * F_;  // [32,128,128,128]

  char* ws = (char*)d_ws;
  float* e_v = (float*)ws;                                   // 2 MB
  uint32_t* wpack = (uint32_t*)(ws + (size_t)2097152);       // 32 KB
  float* pve_part = (float*)(ws + (size_t)2097152 + 65536);  // 8 MB

  ev_kernel<<<(B_ * N_) / 8, 128, 0, stream>>>(v_in, W_ev, b_ev, e_v);
  pack_kernel<<<8, 256, 0, stream>>>(W_e, wpack);
  main_kernel<<<B_ * 8 * SPLIT_, 512, 0, stream>>>(e_in, e_v, b_e,
                                                   (const bf16x8*)wpack,
                                                   e_out, pve_part);
  v_kernel<<<(B_ * N_) / 8, 128, 0, stream>>>(v_in, pve_part, W_v, b_v, v_out);
}